// Round 10
// baseline (1036.582 us; speedup 1.0000x reference)
//
#include <hip/hip_runtime.h>
#include <hip/hip_cooperative_groups.h>

namespace cg = cooperative_groups;

#define B_    4
#define C_    256
#define H_    64
#define W_    64
#define HW_   4096
#define NG_   32
#define CPG_  8
#define KK_   9
#define NOFF_ 18

typedef __attribute__((ext_vector_type(8))) short short8;
typedef __attribute__((ext_vector_type(4))) short short4v;
typedef __attribute__((ext_vector_type(4))) float floatx4;

static __device__ __forceinline__ short f2bf(float f) {
    union { float f; unsigned u; } v; v.f = f;
    unsigned r = v.u + 0x7fff + ((v.u >> 16) & 1);   // RNE
    return (short)(r >> 16);
}
static __device__ __forceinline__ float bf2f(short s) {
    union { unsigned u; float f; } v;
    v.u = ((unsigned)(unsigned short)s) << 16;
    return v.f;
}

// ---------------------------------------------------------------------------
// Phase: GroupNorm-apply + ReLU + transpose -> hbt bf16 [HW][C].
// Block = (b, 64-px tile), 1024 threads.
// ---------------------------------------------------------------------------
static __device__ __forceinline__ void gnt_phase(
    char* smem, int layer, const float* xin, const short* yin,
    const float2* st1, const float* gsum, const float* gss,
    const float* gamma, const float* beta, short* hbt)
{
    unsigned* ltile = (unsigned*)smem;          // 64*132*4 = 33792 B
    float2* sst = (float2*)(smem + 33792);      // 32*8 = 256 B
    int blk = blockIdx.x, t = threadIdx.x;
    int b = blk >> 6;
    int px0 = (blk & 63) * 64;
    if (t < 32) {
        float m, rs;
        if (layer == 1) { float2 v = st1[b * 32 + t]; m = v.x; rs = v.y; }
        else {
            float s = gsum[b * 32 + t], ss = gss[b * 32 + t];
            m = s / 32768.f;
            rs = rsqrtf(ss / 32768.f - m * m + 1e-5f);
        }
        sst[t] = make_float2(m, rs);
    }
    __syncthreads();
    int pq4 = t & 15, cphi = t >> 4;            // cphi 0..63
    #pragma unroll
    for (int i = 0; i < 2; ++i) {
        int cp = i * 64 + cphi;                 // channel pair 0..127
        int c0 = 2 * cp, c1 = c0 + 1;
        float2 st = sst[c0 >> 3];
        float ga0 = gamma[c0] * st.y, be0 = beta[c0] - st.x * ga0;
        float ga1 = gamma[c1] * st.y, be1 = beta[c1] - st.x * ga1;
        short4v lo, hi;
        if (layer == 1) {
            const float* r0 = xin + (size_t)(b * C_ + c0) * HW_ + px0 + pq4 * 4;
            float4 v0 = *(const float4*)r0;
            float4 v1 = *(const float4*)(r0 + HW_);
            lo.x = f2bf(fmaxf(fmaf(v0.x, ga0, be0), 0.f));
            lo.y = f2bf(fmaxf(fmaf(v0.y, ga0, be0), 0.f));
            lo.z = f2bf(fmaxf(fmaf(v0.z, ga0, be0), 0.f));
            lo.w = f2bf(fmaxf(fmaf(v0.w, ga0, be0), 0.f));
            hi.x = f2bf(fmaxf(fmaf(v1.x, ga1, be1), 0.f));
            hi.y = f2bf(fmaxf(fmaf(v1.y, ga1, be1), 0.f));
            hi.z = f2bf(fmaxf(fmaf(v1.z, ga1, be1), 0.f));
            hi.w = f2bf(fmaxf(fmaf(v1.w, ga1, be1), 0.f));
        } else {
            const short* r0 = yin + (size_t)(b * C_ + c0) * HW_ + px0 + pq4 * 4;
            short4v v0 = *(const short4v*)r0;
            short4v v1 = *(const short4v*)(r0 + HW_);
            lo.x = f2bf(fmaxf(fmaf(bf2f(v0.x), ga0, be0), 0.f));
            lo.y = f2bf(fmaxf(fmaf(bf2f(v0.y), ga0, be0), 0.f));
            lo.z = f2bf(fmaxf(fmaf(bf2f(v0.z), ga0, be0), 0.f));
            lo.w = f2bf(fmaxf(fmaf(bf2f(v0.w), ga0, be0), 0.f));
            hi.x = f2bf(fmaxf(fmaf(bf2f(v1.x), ga1, be1), 0.f));
            hi.y = f2bf(fmaxf(fmaf(bf2f(v1.y), ga1, be1), 0.f));
            hi.z = f2bf(fmaxf(fmaf(bf2f(v1.z), ga1, be1), 0.f));
            hi.w = f2bf(fmaxf(fmaf(bf2f(v1.w), ga1, be1), 0.f));
        }
        #pragma unroll
        for (int j = 0; j < 4; ++j) {
            int pl = pq4 * 4 + j;
            unsigned wrd = (unsigned)(unsigned short)lo[j]
                         | ((unsigned)(unsigned short)hi[j] << 16);
            ltile[pl * 132 + (cp ^ ((pl & 7) << 2))] = wrd;
        }
    }
    __syncthreads();
    int co = t & 31, ph = t >> 5;               // ph 0..31
    #pragma unroll
    for (int r = 0; r < 2; ++r) {
        int pl = r * 32 + ph;
        uint4 v = *(const uint4*)&ltile[pl * 132 + ((co * 4) ^ ((pl & 7) << 2))];
        *(uint4*)(hbt + ((size_t)b * HW_ + px0 + pl) * C_ + co * 8) = v;
    }
}

// ---------------------------------------------------------------------------
// Phase: depthwise 7x7 SAME conv with gn-affine+ReLU applied on load.
// Block handles 4 planes (one per 256-thr quarter). Output bf16 [C][HW].
// ---------------------------------------------------------------------------
static __device__ __forceinline__ void dw7_phase(
    char* smem, int layer, const float* xin, const short* yin,
    const float2* st1, const float* gsum, const float* gss,
    const float* gamma, const float* beta, const float* dwk,
    short* fdwc)
{
    int t = threadIdx.x;
    int q = t >> 8, tq = t & 255;
    int plane = blockIdx.x * 4 + q;
    int b = plane >> 8, c = plane & (C_ - 1);
    float* tile = (float*)(smem + q * 20480);   // 70*72 floats
    float* wk = tile + 5040;                    // 49 floats
    float m, rs;
    if (layer == 1) { float2 s = st1[b * 32 + (c >> 3)]; m = s.x; rs = s.y; }
    else {
        float s = gsum[b * 32 + (c >> 3)], ss = gss[b * 32 + (c >> 3)];
        m = s / 32768.f;
        rs = rsqrtf(ss / 32768.f - m * m + 1e-5f);
    }
    float ga = gamma[c] * rs, be = beta[c] - m * ga;
    if (tq < 49) wk[tq] = dwk[c * 49 + tq];
    for (int i = tq; i < 5040; i += 256) tile[i] = 0.f;
    __syncthreads();
    if (layer == 1) {
        const float4* src4 = (const float4*)(xin + (size_t)plane * HW_);
        for (int i = tq; i < 1024; i += 256) {
            float4 v = src4[i];
            int y = i >> 4, xx = (i & 15) * 4;
            float* tp = &tile[(y + 3) * 72 + xx + 3];
            tp[0] = fmaxf(fmaf(v.x, ga, be), 0.f);
            tp[1] = fmaxf(fmaf(v.y, ga, be), 0.f);
            tp[2] = fmaxf(fmaf(v.z, ga, be), 0.f);
            tp[3] = fmaxf(fmaf(v.w, ga, be), 0.f);
        }
    } else {
        const short4v* src4 = (const short4v*)(yin + (size_t)plane * HW_);
        for (int i = tq; i < 1024; i += 256) {
            short4v v = src4[i];
            int y = i >> 4, xx = (i & 15) * 4;
            float* tp = &tile[(y + 3) * 72 + xx + 3];
            tp[0] = fmaxf(fmaf(bf2f(v.x), ga, be), 0.f);
            tp[1] = fmaxf(fmaf(bf2f(v.y), ga, be), 0.f);
            tp[2] = fmaxf(fmaf(bf2f(v.z), ga, be), 0.f);
            tp[3] = fmaxf(fmaf(bf2f(v.w), ga, be), 0.f);
        }
    }
    __syncthreads();
    short* dst = fdwc + (size_t)plane * HW_;
    #pragma unroll
    for (int it = 0; it < 4; ++it) {
        int idx = it * 256 + tq;
        int y = idx >> 4;
        int x0 = (idx & 15) * 4;
        float a0 = 0.f, a1 = 0.f, a2 = 0.f, a3 = 0.f;
        #pragma unroll
        for (int dy = 0; dy < 7; ++dy) {
            const float* tr = &tile[(y + dy) * 72 + x0];
            float4 ra = *(const float4*)tr;
            float4 rb = *(const float4*)(tr + 4);
            float4 rc = *(const float4*)(tr + 8);
            float r[12] = {ra.x, ra.y, ra.z, ra.w,
                           rb.x, rb.y, rb.z, rb.w,
                           rc.x, rc.y, rc.z, rc.w};
            const float* wr = &wk[dy * 7];
            #pragma unroll
            for (int dx = 0; dx < 7; ++dx) {
                float wv = wr[dx];
                a0 = fmaf(r[dx], wv, a0);
                a1 = fmaf(r[dx + 1], wv, a1);
                a2 = fmaf(r[dx + 2], wv, a2);
                a3 = fmaf(r[dx + 3], wv, a3);
            }
        }
        short4v o;
        o.x = f2bf(a0); o.y = f2bf(a1); o.z = f2bf(a2); o.w = f2bf(a3);
        *(short4v*)&dst[y * 64 + x0] = o;
    }
}

// ---------------------------------------------------------------------------
// Phase: fused {f-tile + pw offsets (MFMA) + bilinear + gather + MFMA einsum
// + epilogue (+gn2 stats atomics)}. Block = (b,row), 1024 thr.
// Ping-pong register pipeline: at iteration g, stage_write(g+1) CONSUMES the
// set filled at g-1 ((g&1)?rs0:rs1), then prefetch(g+2) REFILLS that same
// freed set's partner ((g&1)?rs1:rs0).  [R9 bug: both used the same set.]
// ---------------------------------------------------------------------------
static __device__ __forceinline__ void deform_phase(
    char* smem, const short* hbt, const short* fdwc, const short* ppk,
    const float* pwb, const short* wp, const float* bias,
    const float* resid, float* outf, short* outb,
    float* gsum, float* gss)
{
    short* sbufA = (short*)smem;                     // 32 KB
    short* sbufB = (short*)(smem + 32768);           // 32 KB
    int*   pidx  = (int*)(smem + 65536);             // 576*4
    float (*cf)[4] = (float(*)[4])(smem + 67840);    // 576*16
    float* off_lds = (float*)(smem + 77056);         // 1152*4 -> end 81664
    int b = blockIdx.x >> 6;
    int row = blockIdx.x & 63;
    int t = threadIdx.x;
    int wv = t >> 6, lane = t & 63;
    int pq = lane >> 4, pr = lane & 15;

    // ---- f-tile [256c][64px] into LDS (aliases sbufA) ----
    {
        int c = t >> 2, seg = t & 3;
        const short* src = fdwc + (size_t)(b * C_ + c) * HW_ + row * 64;
        *(short8*)&sbufA[c * 64 + seg * 8]       = *(const short8*)(src + seg * 8);
        *(short8*)&sbufA[c * 64 + (seg + 4) * 8] = *(const short8*)(src + (seg + 4) * 8);
    }
    __syncthreads();

    // ---- pw offsets via MFMA (waves 0..7) ----
    if (wv < 8) {
        int ot = wv & 1, ptw = wv >> 1;
        int pxl = ptw * 16 + pr;
        const short8* ap = (const short8*)ppk;
        floatx4 pacc = (floatx4){0.f, 0.f, 0.f, 0.f};
        #pragma unroll
        for (int sl = 0; sl < 8; ++sl) {
            short8 bf;
            int cbase = sl * 32 + pq * 8;
            #pragma unroll
            for (int j = 0; j < 8; ++j) bf[j] = sbufA[(cbase + j) * 64 + pxl];
            short8 af = ap[(sl * 2 + ot) * 64 + lane];
            pacc = __builtin_amdgcn_mfma_f32_16x16x32_bf16(af, bf, pacc, 0, 0, 0);
        }
        #pragma unroll
        for (int r = 0; r < 4; ++r) {
            int o = ot * 16 + pq * 4 + r;
            if (o < NOFF_) off_lds[o * 64 + pxl] = pacc[r] + pwb[o];
        }
    }
    __syncthreads();

    // ---- bilinear tables (576 = 9 taps x 64 px) ----
    if (t < 576) {
        int k = t >> 6, p = t & 63;
        float offy = off_lds[(2 * k) * 64 + p];
        float offx = off_lds[(2 * k + 1) * 64 + p];
        float py = (float)row + (float)(k / 3 - 1) + offy;
        float px = (float)p   + (float)(k % 3 - 1) + offx;
        float y0f = floorf(py), x0f = floorf(px);
        float wy1 = py - y0f, wx1 = px - x0f;
        float wy0 = 1.f - wy1, wx0 = 1.f - wx1;
        float y1f = y0f + 1.f, x1f = x0f + 1.f;
        bool vy0 = (y0f >= 0.f) && (y0f <= 63.f);
        bool vy1 = (y1f >= 0.f) && (y1f <= 63.f);
        bool vx0 = (x0f >= 0.f) && (x0f <= 63.f);
        bool vx1 = (x1f >= 0.f) && (x1f <= 63.f);
        int iy0 = (int)fminf(fmaxf(y0f, 0.f), 63.f);
        int iy1 = (int)fminf(fmaxf(y1f, 0.f), 63.f);
        int ix0 = (int)fminf(fmaxf(x0f, 0.f), 63.f);
        int ix1 = (int)fminf(fmaxf(x1f, 0.f), 63.f);
        pidx[t] = iy0 | (ix0 << 8) | (iy1 << 16) | (ix1 << 24);
        cf[t][0] = (vy0 && vx0) ? wy0 * wx0 : 0.f;
        cf[t][1] = (vy0 && vx1) ? wy0 * wx1 : 0.f;
        cf[t][2] = (vy1 && vx0) ? wy1 * wx0 : 0.f;
        cf[t][3] = (vy1 && vx1) ? wy1 * wx1 : 0.f;
    }
    __syncthreads();

    // ---- 9 groups (taps) x 8 slabs, double-buffered ----
    int ssl0 = t >> 8;
    int spx = (t >> 2) & 63, scb = t & 3;
    int u2 = spx * 4 + (scb ^ ((spx + (spx >> 2)) & 3));
    const short* hb0 = hbt + ((size_t)b * HW_) * C_ + ssl0 * 32 + scb * 8;
    const short* hb1 = hb0 + 128;

    short8 rs0[8], rs1[8];
    auto prefetch = [&](int g, short8* r) {
        int pk = pidx[g * 64 + spx];
        int iy0 = pk & 255, ix0 = (pk >> 8) & 255;
        int iy1 = (pk >> 16) & 255, ix1 = (pk >> 24) & 255;
        size_t a00 = (size_t)(iy0 * 64 + ix0) * C_;
        size_t a01 = (size_t)(iy0 * 64 + ix1) * C_;
        size_t a10 = (size_t)(iy1 * 64 + ix0) * C_;
        size_t a11 = (size_t)(iy1 * 64 + ix1) * C_;
        r[0] = *(const short8*)(hb0 + a00);
        r[1] = *(const short8*)(hb0 + a01);
        r[2] = *(const short8*)(hb0 + a10);
        r[3] = *(const short8*)(hb0 + a11);
        r[4] = *(const short8*)(hb1 + a00);
        r[5] = *(const short8*)(hb1 + a01);
        r[6] = *(const short8*)(hb1 + a10);
        r[7] = *(const short8*)(hb1 + a11);
    };
    auto stage_write = [&](int g, int bi, const short8* r) {
        int e = g * 64 + spx;
        float w00 = cf[e][0], w01 = cf[e][1], w10 = cf[e][2], w11 = cf[e][3];
        short8 va, vb;
        #pragma unroll
        for (int j = 0; j < 8; ++j) {
            va[j] = f2bf(w00 * bf2f(r[0][j]) + w01 * bf2f(r[1][j])
                       + w10 * bf2f(r[2][j]) + w11 * bf2f(r[3][j]));
            vb[j] = f2bf(w00 * bf2f(r[4][j]) + w01 * bf2f(r[5][j])
                       + w10 * bf2f(r[6][j]) + w11 * bf2f(r[7][j]));
        }
        short* sb = bi ? sbufB : sbufA;
        *(short8*)&sb[ssl0 * 2048 + u2 * 8] = va;
        *(short8*)&sb[(ssl0 + 4) * 2048 + u2 * 8] = vb;
    };

    floatx4 acc[4];
    #pragma unroll
    for (int pt = 0; pt < 4; ++pt) acc[pt] = (floatx4){0.f, 0.f, 0.f, 0.f};
    int ub[4];
    #pragma unroll
    for (int pt = 0; pt < 4; ++pt) {
        int px2 = pt * 16 + pr;
        ub[pt] = px2 * 4 + (pq ^ ((px2 + (px2 >> 2)) & 3));
    }

    prefetch(0, rs0);
    stage_write(0, 0, rs0);          // rs0 free
    prefetch(1, rs1);                // rs1 holds g=1
    __syncthreads();

    const short8* wp8 = (const short8*)wp;
    for (int g = 0; g < 9; ++g) {
        const short* sb = (g & 1) ? sbufB : sbufA;
        #pragma unroll
        for (int half = 0; half < 2; ++half) {
            short8 af[4];
            #pragma unroll
            for (int q2 = 0; q2 < 4; ++q2)
                af[q2] = wp8[(size_t)((g * 8 + half * 4 + q2) * 16 + wv) * 64 + lane];
            #pragma unroll
            for (int q2 = 0; q2 < 4; ++q2) {
                int s2 = half * 4 + q2;
                #pragma unroll
                for (int pt = 0; pt < 4; ++pt) {
                    short8 bfv = *(const short8*)&sb[s2 * 2048 + ub[pt] * 8];
                    acc[pt] = __builtin_amdgcn_mfma_f32_16x16x32_bf16(
                        af[q2], bfv, acc[pt], 0, 0, 0);
                }
            }
        }
        if (g + 1 < 9) {
            stage_write(g + 1, (g + 1) & 1, (g & 1) ? rs0 : rs1);  // consume
            if (g + 2 < 9) prefetch(g + 2, (g & 1) ? rs1 : rs0);   // refill freed
        }
        __syncthreads();
    }

    // ---- epilogue ----
    float ssum = 0.f, ssq = 0.f;
    #pragma unroll
    for (int r = 0; r < 4; ++r) {
        int o = wv * 16 + pq * 4 + r;
        float bo = bias[o];
        size_t obase = ((size_t)(b * C_ + o)) * HW_ + row * 64 + pr;
        #pragma unroll
        for (int pt = 0; pt < 4; ++pt) {
            float v = acc[pt][r] + bo;
            if (outf) {
                outf[obase + pt * 16] = v + resid[obase + pt * 16];
            } else {
                short sv = f2bf(v);
                outb[obase + pt * 16] = sv;
                float vq = bf2f(sv);
                ssum += vq; ssq += vq * vq;
            }
        }
    }
    if (outb) {
        #pragma unroll
        for (int d = 1; d < 32; d <<= 1) {
            ssum += __shfl_xor(ssum, d, 64);
            ssq  += __shfl_xor(ssq, d, 64);
        }
        if ((lane & 31) == 0) {
            int grp = wv * 2 + (pq >> 1);
            atomicAdd(&gsum[b * 32 + grp], ssum);
            atomicAdd(&gss[b * 32 + grp], ssq);
        }
    }
}

// ---------------------------------------------------------------------------
// THE kernel: whole residual block in one cooperative launch.
// grid 256 x 1024 (1 block/CU), 4 grid syncs with release+acquire fences.
// ---------------------------------------------------------------------------
__global__ __launch_bounds__(1024) void mono_kernel(
    const float* __restrict__ x,
    const float* __restrict__ gn1_g, const float* __restrict__ gn1_b,
    const float* __restrict__ dw1, const float* __restrict__ pw1,
    const float* __restrict__ pwb1, const float* __restrict__ w1,
    const float* __restrict__ b1,
    const float* __restrict__ gn2_g, const float* __restrict__ gn2_b,
    const float* __restrict__ dw2, const float* __restrict__ pw2,
    const float* __restrict__ pwb2, const float* __restrict__ w2,
    const float* __restrict__ b2,
    float* __restrict__ out,
    short* __restrict__ hbt1, short* __restrict__ fdwc1,
    short* __restrict__ hbt2, short* __restrict__ fdwc2,
    short* __restrict__ y1b,
    short* __restrict__ wp1, short* __restrict__ wp2,
    short* __restrict__ ppk1, short* __restrict__ ppk2,
    float2* __restrict__ st1, float* __restrict__ gsum,
    float* __restrict__ gss)
{
    cg::grid_group grid = cg::this_grid();
    __shared__ __align__(16) char smem[81920];
    int blk = blockIdx.x, t = threadIdx.x;

    // ---- P0: weight packs + gn1 stats + zero gn2 accumulators ----
    if (blk < 128) {
        size_t base = (size_t)blk * CPG_ * HW_;
        const float4* in4 = (const float4*)(x + base);
        float s = 0.f, ss = 0.f;
        for (int i = t; i < 8192; i += 1024) {
            float4 v = in4[i];
            s  += v.x + v.y + v.z + v.w;
            ss += v.x * v.x + v.y * v.y + v.z * v.z + v.w * v.w;
        }
        #pragma unroll
        for (int d = 32; d > 0; d >>= 1) {
            s  += __shfl_down(s, d, 64);
            ss += __shfl_down(ss, d, 64);
        }
        float* red = (float*)smem;
        int wid = t >> 6;
        if ((t & 63) == 0) { red[wid] = s; red[16 + wid] = ss; }
        __syncthreads();
        if (t == 0) {
            float S = 0.f, SS = 0.f;
            #pragma unroll
            for (int i = 0; i < 16; ++i) { S += red[i]; SS += red[16 + i]; }
            float m = S / 32768.f;
            float var = SS / 32768.f - m * m;
            st1[blk] = make_float2(m, rsqrtf(var + 1e-5f));
        }
    } else {
        int tid = (blk - 128) * 1024 + t;           // 0..131071
        for (int idx = tid; idx < 589824; idx += 131072) {
            int j    = idx & 7;
            int lane = (idx >> 3) & 63;
            int ot   = (idx >> 9) & 15;
            int slab = idx >> 13;
            int k = slab >> 3, cc = slab & 7;
            int o = ot * 16 + (lane & 15);
            int c = cc * 32 + (lane >> 4) * 8 + j;
            wp1[idx] = f2bf(w1[(size_t)(o * C_ + c) * KK_ + k]);
            wp2[idx] = f2bf(w2[(size_t)(o * C_ + c) * KK_ + k]);
        }
        if (tid < 8192) {
            int j = tid & 7, lane = (tid >> 3) & 63;
            int ot = (tid >> 9) & 1, sl = tid >> 10;
            int o = ot * 16 + (lane & 15);
            int k = sl * 32 + (lane >> 4) * 8 + j;
            ppk1[tid] = (o < NOFF_) ? f2bf(pw1[o * C_ + k]) : (short)0;
            ppk2[tid] = (o < NOFF_) ? f2bf(pw2[o * C_ + k]) : (short)0;
        }
        if (blk == 128 && t < 128) { gsum[t] = 0.f; gss[t] = 0.f; }
    }
    __threadfence();
    grid.sync();
    __threadfence();

    // ---- P1: gnt L1 + dw7 L1 ----
    gnt_phase(smem, 1, x, nullptr, st1, gsum, gss, gn1_g, gn1_b, hbt1);
    __syncthreads();
    dw7_phase(smem, 1, x, nullptr, st1, gsum, gss, gn1_g, gn1_b, dw1, fdwc1);
    __threadfence();
    grid.sync();
    __threadfence();

    // ---- P2: deform L1 -> y1b (+gn2 stats) ----
    deform_phase(smem, hbt1, fdwc1, ppk1, pwb1, wp1, b1,
                 nullptr, nullptr, y1b, gsum, gss);
    __threadfence();
    grid.sync();
    __threadfence();

    // ---- P3: gnt L2 + dw7 L2 ----
    gnt_phase(smem, 2, nullptr, y1b, st1, gsum, gss, gn2_g, gn2_b, hbt2);
    __syncthreads();
    dw7_phase(smem, 2, nullptr, y1b, st1, gsum, gss, gn2_g, gn2_b, dw2, fdwc2);
    __threadfence();
    grid.sync();
    __threadfence();

    // ---- P4: deform L2 -> out (+ residual x) ----
    deform_phase(smem, hbt2, fdwc2, ppk2, pwb2, wp2, b2,
                 x, out, nullptr, nullptr, nullptr);
}

// ---------------------------------------------------------------------------
extern "C" void kernel_launch(void* const* d_in, const int* in_sizes, int n_in,
                              void* d_out, int out_size, void* d_ws, size_t ws_size,
                              hipStream_t stream)
{
    const float* x     = (const float*)d_in[0];
    const float* gn1_g = (const float*)d_in[1];
    const float* gn1_b = (const float*)d_in[2];
    const float* dw1   = (const float*)d_in[3];
    const float* pw1   = (const float*)d_in[4];
    const float* pwb1  = (const float*)d_in[5];
    const float* w1    = (const float*)d_in[6];
    const float* b1    = (const float*)d_in[7];
    const float* gn2_g = (const float*)d_in[8];
    const float* gn2_b = (const float*)d_in[9];
    const float* dw2   = (const float*)d_in[10];
    const float* pw2   = (const float*)d_in[11];
    const float* pwb2  = (const float*)d_in[12];
    const float* w2    = (const float*)d_in[13];
    const float* b2    = (const float*)d_in[14];
    float* out = (float*)d_out;

    float* ws = (float*)d_ws;
    short* hbt1  = (short*)ws;                   // bf16 [B][HW][C] (8 MB)
    short* fdwc1 = (short*)(ws + 2097152);       // bf16 [B][C][HW] (8 MB)
    short* hbt2  = (short*)(ws + 4194304);       // bf16 [B][HW][C] (8 MB)
    short* fdwc2 = (short*)(ws + 6291456);       // bf16 [B][C][HW] (8 MB)
    short* y1b   = (short*)(ws + 8388608);       // bf16 [B][C][HW] (8 MB)
    short* wp1   = (short*)(ws + 10485760);      // 589,824 bf16
    short* wp2   = (short*)(ws + 10780672);
    short* ppk1  = (short*)(ws + 11075584);      // 8,192 bf16
    short* ppk2  = (short*)(ws + 11079680);
    float2* st1  = (float2*)(ws + 11083776);     // 128 float2
    float* gsum  = ws + 11084032;                // 128
    float* gss   = ws + 11084160;                // 128

    void* args[] = {
        (void*)&x, (void*)&gn1_g, (void*)&gn1_b, (void*)&dw1, (void*)&pw1,
        (void*)&pwb1, (void*)&w1, (void*)&b1, (void*)&gn2_g, (void*)&gn2_b,
        (void*)&dw2, (void*)&pw2, (void*)&pwb2, (void*)&w2, (void*)&b2,
        (void*)&out,
        (void*)&hbt1, (void*)&fdwc1, (void*)&hbt2, (void*)&fdwc2, (void*)&y1b,
        (void*)&wp1, (void*)&wp2, (void*)&ppk1, (void*)&ppk2,
        (void*)&st1, (void*)&gsum, (void*)&gss
    };
    hipLaunchCooperativeKernel((void*)mono_kernel, dim3(256), dim3(1024),
                               args, 0, stream);
}

// Round 11
// 258.946 us; speedup vs baseline: 4.0031x; 4.0031x over previous
//
#include <hip/hip_runtime.h>

#define B_    4
#define C_    256
#define H_    64
#define W_    64
#define HW_   4096
#define NG_   32
#define CPG_  8
#define KK_   9
#define NOFF_ 18

typedef __attribute__((ext_vector_type(8))) short short8;
typedef __attribute__((ext_vector_type(4))) short short4v;
typedef __attribute__((ext_vector_type(4))) float floatx4;

static __device__ __forceinline__ short f2bf(float f) {
    union { float f; unsigned u; } v; v.f = f;
    unsigned r = v.u + 0x7fff + ((v.u >> 16) & 1);   // RNE
    return (short)(r >> 16);
}
static __device__ __forceinline__ float bf2f(short s) {
    union { unsigned u; float f; } v;
    v.u = ((unsigned)(unsigned short)s) << 16;
    return v.f;
}

// ---------------------------------------------------------------------------
// K0: prep — weight packs + gn1 stats + zero gn2-stats accumulators.
// (verbatim R8, measured-good)
// ---------------------------------------------------------------------------
__global__ __launch_bounds__(256) void prep_kernel(
    const float* __restrict__ w1, const float* __restrict__ w2,
    const float* __restrict__ pw1, const float* __restrict__ pw2,
    const float* __restrict__ x,
    short* __restrict__ wp1, short* __restrict__ wp2,
    short* __restrict__ ppk1, short* __restrict__ ppk2,
    float2* __restrict__ stats1, float* __restrict__ gsum,
    float* __restrict__ gss)
{
    int blk = blockIdx.x;
    int t = threadIdx.x;
    if (blk < 4608) {
        const float* w = (blk < 2304) ? w1 : w2;
        short* wp = (blk < 2304) ? wp1 : wp2;
        int idx = (blk % 2304) * 256 + t;
        int j    = idx & 7;
        int lane = (idx >> 3) & 63;
        int ot   = (idx >> 9) & 15;
        int slab = idx >> 13;                        // 0..71
        int k = slab >> 3, cc = slab & 7;
        int o = ot * 16 + (lane & 15);
        int c = cc * 32 + (lane >> 4) * 8 + j;
        wp[idx] = f2bf(w[(size_t)(o * C_ + c) * KK_ + k]);
    } else if (blk < 4672) {
        int q = blk - 4608;                          // 0..63
        const float* pw = (q < 32) ? pw1 : pw2;
        short* ppk = (q < 32) ? ppk1 : ppk2;
        int idx = (q & 31) * 256 + t;                // 0..8191
        int j = idx & 7, lane = (idx >> 3) & 63;
        int ot = (idx >> 9) & 1, sl = idx >> 10;     // 0..7
        int o = ot * 16 + (lane & 15);
        int k = sl * 32 + (lane >> 4) * 8 + j;
        ppk[idx] = (o < NOFF_) ? f2bf(pw[o * C_ + k]) : (short)0;
    } else if (blk < 4800) {
        int q = blk - 4672;                          // 0..127 = (b,g)
        size_t base = (size_t)q * CPG_ * HW_;
        const float4* in4 = (const float4*)(x + base);
        float s = 0.f, ss = 0.f;
        for (int i = t; i < 8192; i += 256) {
            float4 v = in4[i];
            s  += v.x + v.y + v.z + v.w;
            ss += v.x * v.x + v.y * v.y + v.z * v.z + v.w * v.w;
        }
        #pragma unroll
        for (int d = 32; d > 0; d >>= 1) {
            s  += __shfl_down(s, d, 64);
            ss += __shfl_down(ss, d, 64);
        }
        __shared__ float red[8];
        int wid = t >> 6;
        if ((t & 63) == 0) { red[wid] = s; red[4 + wid] = ss; }
        __syncthreads();
        if (t == 0) {
            float S  = red[0] + red[1] + red[2] + red[3];
            float SS = red[4] + red[5] + red[6] + red[7];
            float m = S / 32768.f;
            float var = SS / 32768.f - m * m;
            stats1[q] = make_float2(m, rsqrtf(var + 1e-5f));
        }
    } else {
        if (t < 128) { gsum[t] = 0.f; gss[t] = 0.f; }
    }
}

// ---------------------------------------------------------------------------
// K1: gd — dispatch-parallel {gnt | dw7}; both depend only on {input, stats}.
// blocks 0..255  : GroupNorm-apply + ReLU + LDS transpose -> hbt [HW][C]
// blocks 256..511: GroupNorm-apply (on load) + ReLU + dw7 -> fdwc [C][HW]
// 1024 threads; phases are the correctness-proven mono-kernel versions.
// ---------------------------------------------------------------------------
__global__ __launch_bounds__(1024) void gd_kernel(
    int layer, const float* __restrict__ xin, const short* __restrict__ yin,
    const float2* __restrict__ st1, const float* __restrict__ gsum,
    const float* __restrict__ gss, const float* __restrict__ gamma,
    const float* __restrict__ beta, const float* __restrict__ dwk,
    short* __restrict__ hbt, short* __restrict__ fdwc)
{
    __shared__ __align__(16) char smem[81920];
    int t = threadIdx.x;
    if (blockIdx.x < 256) {
        // ---------------- gnt branch ----------------
        int blk = blockIdx.x;
        unsigned* ltile = (unsigned*)smem;          // 64*132*4
        float2* sst = (float2*)(smem + 33792);
        int b = blk >> 6;
        int px0 = (blk & 63) * 64;
        if (t < 32) {
            float m, rs;
            if (layer == 1) { float2 v = st1[b * 32 + t]; m = v.x; rs = v.y; }
            else {
                float s = gsum[b * 32 + t], ss = gss[b * 32 + t];
                m = s / 32768.f;
                rs = rsqrtf(ss / 32768.f - m * m + 1e-5f);
            }
            sst[t] = make_float2(m, rs);
        }
        __syncthreads();
        int pq4 = t & 15, cphi = t >> 4;            // cphi 0..63
        #pragma unroll
        for (int i = 0; i < 2; ++i) {
            int cp = i * 64 + cphi;                 // channel pair 0..127
            int c0 = 2 * cp, c1 = c0 + 1;
            float2 st = sst[c0 >> 3];
            float ga0 = gamma[c0] * st.y, be0 = beta[c0] - st.x * ga0;
            float ga1 = gamma[c1] * st.y, be1 = beta[c1] - st.x * ga1;
            short4v lo, hi;
            if (layer == 1) {
                const float* r0 = xin + (size_t)(b * C_ + c0) * HW_ + px0 + pq4 * 4;
                float4 v0 = *(const float4*)r0;
                float4 v1 = *(const float4*)(r0 + HW_);
                lo.x = f2bf(fmaxf(fmaf(v0.x, ga0, be0), 0.f));
                lo.y = f2bf(fmaxf(fmaf(v0.y, ga0, be0), 0.f));
                lo.z = f2bf(fmaxf(fmaf(v0.z, ga0, be0), 0.f));
                lo.w = f2bf(fmaxf(fmaf(v0.w, ga0, be0), 0.f));
                hi.x = f2bf(fmaxf(fmaf(v1.x, ga1, be1), 0.f));
                hi.y = f2bf(fmaxf(fmaf(v1.y, ga1, be1), 0.f));
                hi.z = f2bf(fmaxf(fmaf(v1.z, ga1, be1), 0.f));
                hi.w = f2bf(fmaxf(fmaf(v1.w, ga1, be1), 0.f));
            } else {
                const short* r0 = yin + (size_t)(b * C_ + c0) * HW_ + px0 + pq4 * 4;
                short4v v0 = *(const short4v*)r0;
                short4v v1 = *(const short4v*)(r0 + HW_);
                lo.x = f2bf(fmaxf(fmaf(bf2f(v0.x), ga0, be0), 0.f));
                lo.y = f2bf(fmaxf(fmaf(bf2f(v0.y), ga0, be0), 0.f));
                lo.z = f2bf(fmaxf(fmaf(bf2f(v0.z), ga0, be0), 0.f));
                lo.w = f2bf(fmaxf(fmaf(bf2f(v0.w), ga0, be0), 0.f));
                hi.x = f2bf(fmaxf(fmaf(bf2f(v1.x), ga1, be1), 0.f));
                hi.y = f2bf(fmaxf(fmaf(bf2f(v1.y), ga1, be1), 0.f));
                hi.z = f2bf(fmaxf(fmaf(bf2f(v1.z), ga1, be1), 0.f));
                hi.w = f2bf(fmaxf(fmaf(bf2f(v1.w), ga1, be1), 0.f));
            }
            #pragma unroll
            for (int j = 0; j < 4; ++j) {
                int pl = pq4 * 4 + j;
                unsigned wrd = (unsigned)(unsigned short)lo[j]
                             | ((unsigned)(unsigned short)hi[j] << 16);
                ltile[pl * 132 + (cp ^ ((pl & 7) << 2))] = wrd;
            }
        }
        __syncthreads();
        int co = t & 31, ph = t >> 5;               // ph 0..31
        #pragma unroll
        for (int r = 0; r < 2; ++r) {
            int pl = r * 32 + ph;
            uint4 v = *(const uint4*)&ltile[pl * 132 + ((co * 4) ^ ((pl & 7) << 2))];
            *(uint4*)(hbt + ((size_t)b * HW_ + px0 + pl) * C_ + co * 8) = v;
        }
    } else {
        // ---------------- dw7 branch (gn applied on load) ----------------
        int blk = blockIdx.x - 256;
        int q = t >> 8, tq = t & 255;
        int plane = blk * 4 + q;
        int b = plane >> 8, c = plane & (C_ - 1);
        float* tile = (float*)(smem + q * 20480);   // 70*72 floats
        float* wk = tile + 5040;                    // 49 floats
        float m, rs;
        if (layer == 1) { float2 s = st1[b * 32 + (c >> 3)]; m = s.x; rs = s.y; }
        else {
            float s = gsum[b * 32 + (c >> 3)], ss = gss[b * 32 + (c >> 3)];
            m = s / 32768.f;
            rs = rsqrtf(ss / 32768.f - m * m + 1e-5f);
        }
        float ga = gamma[c] * rs, be = beta[c] - m * ga;
        if (tq < 49) wk[tq] = dwk[c * 49 + tq];
        for (int i = tq; i < 5040; i += 256) tile[i] = 0.f;
        __syncthreads();
        if (layer == 1) {
            const float4* src4 = (const float4*)(xin + (size_t)plane * HW_);
            for (int i = tq; i < 1024; i += 256) {
                float4 v = src4[i];
                int y = i >> 4, xx = (i & 15) * 4;
                float* tp = &tile[(y + 3) * 72 + xx + 3];
                tp[0] = fmaxf(fmaf(v.x, ga, be), 0.f);
                tp[1] = fmaxf(fmaf(v.y, ga, be), 0.f);
                tp[2] = fmaxf(fmaf(v.z, ga, be), 0.f);
                tp[3] = fmaxf(fmaf(v.w, ga, be), 0.f);
            }
        } else {
            const short4v* src4 = (const short4v*)(yin + (size_t)plane * HW_);
            for (int i = tq; i < 1024; i += 256) {
                short4v v = src4[i];
                int y = i >> 4, xx = (i & 15) * 4;
                float* tp = &tile[(y + 3) * 72 + xx + 3];
                tp[0] = fmaxf(fmaf(bf2f(v.x), ga, be), 0.f);
                tp[1] = fmaxf(fmaf(bf2f(v.y), ga, be), 0.f);
                tp[2] = fmaxf(fmaf(bf2f(v.z), ga, be), 0.f);
                tp[3] = fmaxf(fmaf(bf2f(v.w), ga, be), 0.f);
            }
        }
        __syncthreads();
        short* dst = fdwc + (size_t)plane * HW_;
        #pragma unroll
        for (int it = 0; it < 4; ++it) {
            int idx = it * 256 + tq;
            int y = idx >> 4;
            int x0 = (idx & 15) * 4;
            float a0 = 0.f, a1 = 0.f, a2 = 0.f, a3 = 0.f;
            #pragma unroll
            for (int dy = 0; dy < 7; ++dy) {
                const float* tr = &tile[(y + dy) * 72 + x0];
                float4 ra = *(const float4*)tr;
                float4 rb = *(const float4*)(tr + 4);
                float4 rc = *(const float4*)(tr + 8);
                float r[12] = {ra.x, ra.y, ra.z, ra.w,
                               rb.x, rb.y, rb.z, rb.w,
                               rc.x, rc.y, rc.z, rc.w};
                const float* wr = &wk[dy * 7];
                #pragma unroll
                for (int dx = 0; dx < 7; ++dx) {
                    float wv = wr[dx];
                    a0 = fmaf(r[dx], wv, a0);
                    a1 = fmaf(r[dx + 1], wv, a1);
                    a2 = fmaf(r[dx + 2], wv, a2);
                    a3 = fmaf(r[dx + 3], wv, a3);
                }
            }
            short4v o;
            o.x = f2bf(a0); o.y = f2bf(a1); o.z = f2bf(a2); o.w = f2bf(a3);
            *(short4v*)&dst[y * 64 + x0] = o;
        }
    }
}

// ---------------------------------------------------------------------------
// K2: fused deform (verbatim R8's measured 55.4 µs kernel).
// ---------------------------------------------------------------------------
__global__ __launch_bounds__(1024, 4) void deform_fused_kernel(
    const short* __restrict__ hbt,  const short* __restrict__ fdwc,
    const short* __restrict__ ppk,  const float* __restrict__ pwb,
    const short* __restrict__ wp,   const float* __restrict__ bias,
    const float* __restrict__ resid, float* __restrict__ outf,
    short* __restrict__ outb, float* __restrict__ gsum,
    float* __restrict__ gss)
{
    int b = blockIdx.x >> 6;
    int row = blockIdx.x & 63;
    __shared__ __align__(16) short sbuf[2][16384];   // 2 x 32KB
    __shared__ int   pidx[576];
    __shared__ float cf[576][4];
    __shared__ float off_lds[NOFF_ * 64];
    int t = threadIdx.x;
    int wv = t >> 6, lane = t & 63;
    int pq = lane >> 4, pr = lane & 15;

    // ---- stage 0: f-tile [256c][64px] into LDS (aliases sbuf[0]) ----
    {
        int c = t >> 2, seg = t & 3;
        const short* src = fdwc + (size_t)(b * C_ + c) * HW_ + row * 64;
        *(short8*)&sbuf[0][c * 64 + seg * 8]       = *(const short8*)(src + seg * 8);
        *(short8*)&sbuf[0][c * 64 + (seg + 4) * 8] = *(const short8*)(src + (seg + 4) * 8);
    }
    __syncthreads();

    // ---- stage A: pw offsets via MFMA (waves 0..7) ----
    if (wv < 8) {
        int ot = wv & 1, ptw = wv >> 1;
        int pxl = ptw * 16 + pr;
        const short8* ap = (const short8*)ppk;
        floatx4 pacc = (floatx4){0.f, 0.f, 0.f, 0.f};
        #pragma unroll
        for (int sl = 0; sl < 8; ++sl) {
            short8 bf;
            int cbase = sl * 32 + pq * 8;
            #pragma unroll
            for (int j = 0; j < 8; ++j) bf[j] = sbuf[0][(cbase + j) * 64 + pxl];
            short8 af = ap[(sl * 2 + ot) * 64 + lane];
            pacc = __builtin_amdgcn_mfma_f32_16x16x32_bf16(af, bf, pacc, 0, 0, 0);
        }
        #pragma unroll
        for (int r = 0; r < 4; ++r) {
            int o = ot * 16 + pq * 4 + r;
            if (o < NOFF_) off_lds[o * 64 + pxl] = pacc[r] + pwb[o];
        }
    }
    __syncthreads();

    // ---- stage B: bilinear tables (576 = 9 taps x 64 px) ----
    if (t < 576) {
        int k = t >> 6, p = t & 63;
        float offy = off_lds[(2 * k) * 64 + p];
        float offx = off_lds[(2 * k + 1) * 64 + p];
        float py = (float)row + (float)(k / 3 - 1) + offy;
        float px = (float)p   + (float)(k % 3 - 1) + offx;
        float y0f = floorf(py), x0f = floorf(px);
        float wy1 = py - y0f, wx1 = px - x0f;
        float wy0 = 1.f - wy1, wx0 = 1.f - wx1;
        float y1f = y0f + 1.f, x1f = x0f + 1.f;
        bool vy0 = (y0f >= 0.f) && (y0f <= 63.f);
        bool vy1 = (y1f >= 0.f) && (y1f <= 63.f);
        bool vx0 = (x0f >= 0.f) && (x0f <= 63.f);
        bool vx1 = (x1f >= 0.f) && (x1f <= 63.f);
        int iy0 = (int)fminf(fmaxf(y0f, 0.f), 63.f);
        int iy1 = (int)fminf(fmaxf(y1f, 0.f), 63.f);
        int ix0 = (int)fminf(fmaxf(x0f, 0.f), 63.f);
        int ix1 = (int)fminf(fmaxf(x1f, 0.f), 63.f);
        pidx[t] = iy0 | (ix0 << 8) | (iy1 << 16) | (ix1 << 24);
        cf[t][0] = (vy0 && vx0) ? wy0 * wx0 : 0.f;
        cf[t][1] = (vy0 && vx1) ? wy0 * wx1 : 0.f;
        cf[t][2] = (vy1 && vx0) ? wy1 * wx0 : 0.f;
        cf[t][3] = (vy1 && vx1) ? wy1 * wx1 : 0.f;
    }
    __syncthreads();

    // ---- stage C: 9 groups (taps) x 8 slabs, ping-pong pipelined ----
    int ssl0 = t >> 8;
    int spx = (t >> 2) & 63, scb = t & 3;
    int u2 = spx * 4 + (scb ^ ((spx + (spx >> 2)) & 3));
    const short* hb0 = hbt + ((size_t)b * HW_) * C_ + ssl0 * 32 + scb * 8;
    const short* hb1 = hb0 + 128;

    short8 rs0[8], rs1[8];
    auto prefetch = [&](int g, short8* r) {
        int pk = pidx[g * 64 + spx];
        int iy0 = pk & 255, ix0 = (pk >> 8) & 255;
        int iy1 = (pk >> 16) & 255, ix1 = (pk >> 24) & 255;
        size_t a00 = (size_t)(iy0 * 64 + ix0) * C_;
        size_t a01 = (size_t)(iy0 * 64 + ix1) * C_;
        size_t a10 = (size_t)(iy1 * 64 + ix0) * C_;
        size_t a11 = (size_t)(iy1 * 64 + ix1) * C_;
        r[0] = *(const short8*)(hb0 + a00);
        r[1] = *(const short8*)(hb0 + a01);
        r[2] = *(const short8*)(hb0 + a10);
        r[3] = *(const short8*)(hb0 + a11);
        r[4] = *(const short8*)(hb1 + a00);
        r[5] = *(const short8*)(hb1 + a01);
        r[6] = *(const short8*)(hb1 + a10);
        r[7] = *(const short8*)(hb1 + a11);
    };
    auto stage_write = [&](int g, int bi, const short8* r) {
        int e = g * 64 + spx;
        float w00 = cf[e][0], w01 = cf[e][1], w10 = cf[e][2], w11 = cf[e][3];
        short8 va, vb;
        #pragma unroll
        for (int j = 0; j < 8; ++j) {
            va[j] = f2bf(w00 * bf2f(r[0][j]) + w01 * bf2f(r[1][j])
                       + w10 * bf2f(r[2][j]) + w11 * bf2f(r[3][j]));
            vb[j] = f2bf(w00 * bf2f(r[4][j]) + w01 * bf2f(r[5][j])
                       + w10 * bf2f(r[6][j]) + w11 * bf2f(r[7][j]));
        }
        short* sb = sbuf[bi];
        *(short8*)&sb[ssl0 * 2048 + u2 * 8] = va;
        *(short8*)&sb[(ssl0 + 4) * 2048 + u2 * 8] = vb;
    };

    floatx4 acc[4];
    #pragma unroll
    for (int pt = 0; pt < 4; ++pt) acc[pt] = (floatx4){0.f, 0.f, 0.f, 0.f};
    int ub[4];
    #pragma unroll
    for (int pt = 0; pt < 4; ++pt) {
        int px2 = pt * 16 + pr;
        ub[pt] = px2 * 4 + (pq ^ ((px2 + (px2 >> 2)) & 3));
    }

    prefetch(0, rs0);
    stage_write(0, 0, rs0);
    prefetch(1, rs1);
    __syncthreads();

    const short8* wp8 = (const short8*)wp;
    #pragma unroll
    for (int g = 0; g < 9; ++g) {
        if (g + 2 < 9) prefetch(g + 2, (g & 1) ? rs1 : rs0);
        const short* sb = sbuf[g & 1];
        #pragma unroll
        for (int half = 0; half < 2; ++half) {
            short8 af[4];
            #pragma unroll
            for (int q2 = 0; q2 < 4; ++q2)
                af[q2] = wp8[(size_t)((g * 8 + half * 4 + q2) * 16 + wv) * 64 + lane];
            #pragma unroll
            for (int q2 = 0; q2 < 4; ++q2) {
                int s2 = half * 4 + q2;
                #pragma unroll
                for (int pt = 0; pt < 4; ++pt) {
                    short8 bfv = *(const short8*)&sb[s2 * 2048 + ub[pt] * 8];
                    acc[pt] = __builtin_amdgcn_mfma_f32_16x16x32_bf16(
                        af[q2], bfv, acc[pt], 0, 0, 0);
                }
            }
        }
        if (g + 1 < 9)
            stage_write(g + 1, (g + 1) & 1, (g & 1) ? rs0 : rs1);
        __syncthreads();
    }

    // ---- epilogue (+ gn2 stats when writing bf16) ----
    float ssum = 0.f, ssq = 0.f;
    #pragma unroll
    for (int r = 0; r < 4; ++r) {
        int o = wv * 16 + pq * 4 + r;
        float bo = bias[o];
        size_t obase = ((size_t)(b * C_ + o)) * HW_ + row * 64 + pr;
        #pragma unroll
        for (int pt = 0; pt < 4; ++pt) {
            float v = acc[pt][r] + bo;
            if (outf) {
                outf[obase + pt * 16] = v + resid[obase + pt * 16];
            } else {
                short sv = f2bf(v);
                outb[obase + pt * 16] = sv;
                float vq = bf2f(sv);
                ssum += vq; ssq += vq * vq;
            }
        }
    }
    if (outb) {
        #pragma unroll
        for (int d = 1; d < 32; d <<= 1) {
            ssum += __shfl_xor(ssum, d, 64);
            ssq  += __shfl_xor(ssq, d, 64);
        }
        if ((lane & 31) == 0) {
            int grp = wv * 2 + (pq >> 1);
            atomicAdd(&gsum[b * 32 + grp], ssum);
            atomicAdd(&gss[b * 32 + grp], ssq);
        }
    }
}

// ---------------------------------------------------------------------------
extern "C" void kernel_launch(void* const* d_in, const int* in_sizes, int n_in,
                              void* d_out, int out_size, void* d_ws, size_t ws_size,
                              hipStream_t stream)
{
    const float* x     = (const float*)d_in[0];
    const float* gn1_g = (const float*)d_in[1];
    const float* gn1_b = (const float*)d_in[2];
    const float* dw1   = (const float*)d_in[3];
    const float* pw1   = (const float*)d_in[4];
    const float* pwb1  = (const float*)d_in[5];
    const float* w1    = (const float*)d_in[6];
    const float* b1    = (const float*)d_in[7];
    const float* gn2_g = (const float*)d_in[8];
    const float* gn2_b = (const float*)d_in[9];
    const float* dw2   = (const float*)d_in[10];
    const float* pw2   = (const float*)d_in[11];
    const float* pwb2  = (const float*)d_in[12];
    const float* w2    = (const float*)d_in[13];
    const float* b2    = (const float*)d_in[14];
    float* out = (float*)d_out;

    float* ws = (float*)d_ws;
    short* y1b   = (short*)ws;                   // bf16 [B][C][HW] (8 MB)
    short* hbt   = (short*)(ws + 2097152);       // bf16 [B][HW][C] (8 MB)
    short* fdwc  = (short*)(ws + 4194304);       // bf16 [B][C][HW] (8 MB)
    short* wp1   = (short*)(ws + 6291456);       // 589,824 bf16
    short* wp2   = (short*)(ws + 6586368);
    short* ppk1  = (short*)(ws + 6881280);       // 8,192 bf16
    short* ppk2  = (short*)(ws + 6885376);
    float2* st1  = (float2*)(ws + 6889472);      // 128 float2
    float* gsum  = ws + 6889728;                 // 128
    float* gss   = ws + 6889856;                 // 128

    prep_kernel<<<4801, 256, 0, stream>>>(w1, w2, pw1, pw2, x,
                                          wp1, wp2, ppk1, ppk2,
                                          st1, gsum, gss);

    // layer 1
    gd_kernel<<<512, 1024, 0, stream>>>(1, x, nullptr, st1, gsum, gss,
                                        gn1_g, gn1_b, dw1, hbt, fdwc);
    deform_fused_kernel<<<B_ * H_, 1024, 0, stream>>>(
        hbt, fdwc, ppk1, pwb1, wp1, b1, nullptr, nullptr, y1b, gsum, gss);

    // layer 2 (+ residual x)
    gd_kernel<<<512, 1024, 0, stream>>>(2, nullptr, y1b, st1, gsum, gss,
                                        gn2_g, gn2_b, dw2, hbt, fdwc);
    deform_fused_kernel<<<B_ * H_, 1024, 0, stream>>>(
        hbt, fdwc, ppk2, pwb2, wp2, b2, x, out, nullptr, nullptr, nullptr);
}